// Round 1
// baseline (333.435 us; speedup 1.0000x reference)
//
#include <hip/hip_runtime.h>
#include <hip/hip_bf16.h>

// Problem constants (B=4096, D=1024 per reference setup_inputs)
#define B_ROWS 4096
#define D_DIM  1024
#define N_ROWS 8192          // 2B
#define TEMP_INV 2.0f        // 1 / 0.5

typedef __attribute__((ext_vector_type(8))) short  bf16x8;  // 8 bf16 = 4 VGPRs
typedef __attribute__((ext_vector_type(4))) float  f32x4;   // MFMA C/D frag

__device__ inline ushort f2bf(float f) {
    union { float f; unsigned u; } v; v.f = f;
    unsigned r = v.u + 0x7fff + ((v.u >> 16) & 1);   // RNE
    return (ushort)(r >> 16);
}

// ---------------------------------------------------------------------------
// Kernel 1: per-row L2 norms of emb_i / emb_j, write normalized bf16 reps
// [8192][1024], positives pos[b] = z_i(b) . z_j(b), and zero denom[8192].
// One block per row pair b. 256 threads, 4 fp32 elements each.
// ---------------------------------------------------------------------------
__global__ __launch_bounds__(256)
void normalize_kernel(const float* __restrict__ emb_i,
                      const float* __restrict__ emb_j,
                      ushort* __restrict__ reps,
                      float* __restrict__ pos,
                      float* __restrict__ denom) {
    const int b = blockIdx.x;     // 0..4095
    const int t = threadIdx.x;    // 0..255

    if (b < N_ROWS / 256) denom[b * 256 + t] = 0.0f;   // blocks 0..31 zero denom

    const float4 vi = ((const float4*)(emb_i + (size_t)b * D_DIM))[t];
    const float4 vj = ((const float4*)(emb_j + (size_t)b * D_DIM))[t];

    float si = vi.x*vi.x + vi.y*vi.y + vi.z*vi.z + vi.w*vi.w;
    float sj = vj.x*vj.x + vj.y*vj.y + vj.z*vj.z + vj.w*vj.w;
    float sd = vi.x*vj.x + vi.y*vj.y + vi.z*vj.z + vi.w*vj.w;

    // wave reduce (64 lanes)
    #pragma unroll
    for (int off = 32; off >= 1; off >>= 1) {
        si += __shfl_xor(si, off);
        sj += __shfl_xor(sj, off);
        sd += __shfl_xor(sd, off);
    }
    __shared__ float red[3][4];
    const int wave = t >> 6;
    if ((t & 63) == 0) { red[0][wave] = si; red[1][wave] = sj; red[2][wave] = sd; }
    __syncthreads();
    si = red[0][0] + red[0][1] + red[0][2] + red[0][3];
    sj = red[1][0] + red[1][1] + red[1][2] + red[1][3];
    sd = red[2][0] + red[2][1] + red[2][2] + red[2][3];

    const float inv_i = 1.0f / fmaxf(sqrtf(si), 1e-12f);
    const float inv_j = 1.0f / fmaxf(sqrtf(sj), 1e-12f);
    if (t == 0) pos[b] = sd * inv_i * inv_j;

    ushort4 oi, oj;
    oi.x = f2bf(vi.x * inv_i); oi.y = f2bf(vi.y * inv_i);
    oi.z = f2bf(vi.z * inv_i); oi.w = f2bf(vi.w * inv_i);
    oj.x = f2bf(vj.x * inv_j); oj.y = f2bf(vj.y * inv_j);
    oj.z = f2bf(vj.z * inv_j); oj.w = f2bf(vj.w * inv_j);
    ((ushort4*)(reps + (size_t)b * D_DIM))[t]            = oi;
    ((ushort4*)(reps + (size_t)(b + B_ROWS) * D_DIM))[t] = oj;
}

// ---------------------------------------------------------------------------
// Kernel 2: fused sim = Z.Z^T -> exp(s/T) -> diag-mask -> column-sum into
// denom[] (valid because sim is symmetric: col sums == row sums).
// 128x128 output tile per block-iteration, BK=32, 16x16x32 bf16 MFMA.
// Grid = 64 row-tiles x 16 col-splits; each block does 4 col-tile iters.
// ---------------------------------------------------------------------------
#define BM 128
#define BN 128
#define BK 32
#define COL_SPLIT 16
#define COLS_PER_BLOCK (N_ROWS / COL_SPLIT)   // 512
#define LDS_STRIDE 40                         // 32 bf16 + 8 pad (16B-aligned rows)

__global__ __launch_bounds__(256)
void sim_denom_kernel(const ushort* __restrict__ reps,
                      float* __restrict__ denom) {
    const int rt = blockIdx.x & 63;       // row tile index
    const int cs = blockIdx.x >> 6;       // col split index
    const int rowBase  = rt * BM;
    const int colStart = cs * COLS_PER_BLOCK;

    const int t    = threadIdx.x;
    const int lane = t & 63;
    const int wave = t >> 6;
    const int wr   = wave >> 1;           // wave row quadrant (0/1)
    const int wc   = wave & 1;            // wave col quadrant (0/1)
    const int quad = lane >> 4;           // 0..3
    const int l15  = lane & 15;

    __shared__ ushort Asmem[BM * LDS_STRIDE];
    __shared__ ushort Bsmem[BN * LDS_STRIDE];

    for (int ci = 0; ci < COLS_PER_BLOCK / BN; ci++) {
        const int colBase = colStart + ci * BN;

        f32x4 acc[4][4];
        #pragma unroll
        for (int mi = 0; mi < 4; mi++)
            #pragma unroll
            for (int ni = 0; ni < 4; ni++)
                acc[mi][ni] = (f32x4){0.f, 0.f, 0.f, 0.f};

        for (int kb = 0; kb < D_DIM; kb += BK) {
            __syncthreads();   // LDS reuse guard (prev iter's reads done)
            // stage A (128x32) and B (128x32) tiles: 512 chunks of 16B each
            #pragma unroll
            for (int c = t; c < (BM * BK) / 8; c += 256) {
                const int row = c >> 2;          // 4 chunks (32 bf16) per row
                const int ko  = (c & 3) * 8;
                bf16x8 va = *(const bf16x8*)(reps + (size_t)(rowBase + row) * D_DIM + kb + ko);
                *(bf16x8*)(Asmem + row * LDS_STRIDE + ko) = va;
                bf16x8 vb = *(const bf16x8*)(reps + (size_t)(colBase + row) * D_DIM + kb + ko);
                *(bf16x8*)(Bsmem + row * LDS_STRIDE + ko) = vb;
            }
            __syncthreads();

            bf16x8 af[4], bfr[4];
            #pragma unroll
            for (int mi = 0; mi < 4; mi++)
                af[mi] = *(const bf16x8*)(Asmem + (wr * 64 + mi * 16 + l15) * LDS_STRIDE + quad * 8);
            #pragma unroll
            for (int ni = 0; ni < 4; ni++)
                bfr[ni] = *(const bf16x8*)(Bsmem + (wc * 64 + ni * 16 + l15) * LDS_STRIDE + quad * 8);

            #pragma unroll
            for (int mi = 0; mi < 4; mi++)
                #pragma unroll
                for (int ni = 0; ni < 4; ni++)
                    acc[mi][ni] = __builtin_amdgcn_mfma_f32_16x16x32_bf16(
                        af[mi], bfr[ni], acc[mi][ni], 0, 0, 0);
        }

        // Epilogue: e = exp(s/T), mask diagonal, accumulate per-lane partial
        // column sums (C layout: col = lane&15, row = quad*4 + reg).
        float cs_part[4] = {0.f, 0.f, 0.f, 0.f};
        #pragma unroll
        for (int mi = 0; mi < 4; mi++) {
            const int rowA = rowBase + wr * 64 + mi * 16 + quad * 4;
            #pragma unroll
            for (int ni = 0; ni < 4; ni++) {
                const int col = colBase + wc * 64 + ni * 16 + l15;
                const f32x4 a = acc[mi][ni];
                #pragma unroll
                for (int r = 0; r < 4; r++) {
                    float e = __expf(a[r] * TEMP_INV);
                    if (rowA + r == col) e = 0.0f;   // neg_mask diagonal
                    cs_part[ni] += e;
                }
            }
        }
        // reduce partial col sums across the 4 quads (lanes l, l^16, l^32)
        #pragma unroll
        for (int ni = 0; ni < 4; ni++) {
            float v = cs_part[ni];
            v += __shfl_xor(v, 16);
            v += __shfl_xor(v, 32);
            cs_part[ni] = v;
        }
        if (quad == 0) {
            #pragma unroll
            for (int ni = 0; ni < 4; ni++) {
                const int col = colBase + wc * 64 + ni * 16 + l15;
                atomicAdd(denom + col, cs_part[ni]);
            }
        }
    }
}

// ---------------------------------------------------------------------------
// Kernel 3: loss = mean over 2B rows of (log(denom) - pos/T). Single block.
// ---------------------------------------------------------------------------
__global__ __launch_bounds__(256)
void loss_kernel(const float* __restrict__ denom,
                 const float* __restrict__ pos,
                 float* __restrict__ out) {
    const int t = threadIdx.x;
    float s = 0.f;
    for (int i = t; i < N_ROWS; i += 256) {
        const float p = pos[i & (B_ROWS - 1)];
        s += logf(denom[i]) - p * TEMP_INV;
    }
    #pragma unroll
    for (int off = 32; off >= 1; off >>= 1) s += __shfl_xor(s, off);
    __shared__ float red[4];
    if ((t & 63) == 0) red[t >> 6] = s;
    __syncthreads();
    if (t == 0) out[0] = (red[0] + red[1] + red[2] + red[3]) / (float)N_ROWS;
}

// ---------------------------------------------------------------------------
extern "C" void kernel_launch(void* const* d_in, const int* in_sizes, int n_in,
                              void* d_out, int out_size, void* d_ws, size_t ws_size,
                              hipStream_t stream) {
    const float* emb_i = (const float*)d_in[0];
    const float* emb_j = (const float*)d_in[1];

    ushort* reps  = (ushort*)d_ws;                                    // 16 MB bf16 [8192][1024]
    float*  pos   = (float*)((char*)d_ws + (size_t)N_ROWS * D_DIM * sizeof(ushort)); // 16 KB
    float*  denom = pos + B_ROWS;                                     // 32 KB
    float*  out   = (float*)d_out;

    normalize_kernel<<<B_ROWS, 256, 0, stream>>>(emb_i, emb_j, reps, pos, denom);
    sim_denom_kernel<<<64 * COL_SPLIT, 256, 0, stream>>>(reps, denom);
    loss_kernel<<<1, 256, 0, stream>>>(denom, pos, out);
}

// Round 2
// 271.198 us; speedup vs baseline: 1.2295x; 1.2295x over previous
//
#include <hip/hip_runtime.h>
#include <hip/hip_bf16.h>

// Problem constants (B=4096, D=1024 per reference setup_inputs)
#define B_ROWS 4096
#define D_DIM  1024
#define N_ROWS 8192          // 2B
#define TEMP_INV 2.0f        // 1 / 0.5

typedef __attribute__((ext_vector_type(8))) short  bf16x8;  // 8 bf16 = 4 VGPRs
typedef __attribute__((ext_vector_type(4))) float  f32x4;   // MFMA C/D frag

__device__ inline ushort f2bf(float f) {
    union { float f; unsigned u; } v; v.f = f;
    unsigned r = v.u + 0x7fff + ((v.u >> 16) & 1);   // RNE
    return (ushort)(r >> 16);
}

// Async global->LDS DMA, 16 B per lane. LDS dest is WAVE-UNIFORM base;
// lane i's 16 B land at base + i*16 (per-lane global addr is free-form).
__device__ inline void load_lds16(const ushort* g, ushort* l) {
    __builtin_amdgcn_global_load_lds(
        (const __attribute__((address_space(1))) unsigned int*)g,
        (__attribute__((address_space(3))) unsigned int*)l,
        16, 0, 0);
}

// ---------------------------------------------------------------------------
// Kernel 1: wave-per-row L2 normalize. Block = 4 waves = 4 row pairs.
// Writes normalized bf16 reps [8192][1024], pos[b] = z_i(b).z_j(b),
// zeroes denom[8192].
// ---------------------------------------------------------------------------
__global__ __launch_bounds__(256)
void normalize_kernel(const float* __restrict__ emb_i,
                      const float* __restrict__ emb_j,
                      ushort* __restrict__ reps,
                      float* __restrict__ pos,
                      float* __restrict__ denom) {
    const int t    = threadIdx.x;
    const int lane = t & 63;
    const int wave = t >> 6;
    const int b    = blockIdx.x * 4 + wave;          // 0..4095

    if (blockIdx.x < N_ROWS / 256) denom[blockIdx.x * 256 + t] = 0.0f;

    const float4* pi = (const float4*)(emb_i + (size_t)b * D_DIM) + lane * 4;
    const float4* pj = (const float4*)(emb_j + (size_t)b * D_DIM) + lane * 4;

    float4 vi[4], vj[4];
    float si = 0.f, sj = 0.f, sd = 0.f;
    #pragma unroll
    for (int k = 0; k < 4; k++) {
        vi[k] = pi[k]; vj[k] = pj[k];
        si += vi[k].x*vi[k].x + vi[k].y*vi[k].y + vi[k].z*vi[k].z + vi[k].w*vi[k].w;
        sj += vj[k].x*vj[k].x + vj[k].y*vj[k].y + vj[k].z*vj[k].z + vj[k].w*vj[k].w;
        sd += vi[k].x*vj[k].x + vi[k].y*vj[k].y + vi[k].z*vj[k].z + vi[k].w*vj[k].w;
    }
    #pragma unroll
    for (int off = 32; off >= 1; off >>= 1) {   // butterfly: all lanes get sums
        si += __shfl_xor(si, off);
        sj += __shfl_xor(sj, off);
        sd += __shfl_xor(sd, off);
    }
    const float inv_i = 1.0f / fmaxf(sqrtf(si), 1e-12f);
    const float inv_j = 1.0f / fmaxf(sqrtf(sj), 1e-12f);
    if (lane == 0) pos[b] = sd * inv_i * inv_j;

    ushort oi[16], oj[16];
    #pragma unroll
    for (int k = 0; k < 4; k++) {
        oi[4*k+0] = f2bf(vi[k].x * inv_i); oi[4*k+1] = f2bf(vi[k].y * inv_i);
        oi[4*k+2] = f2bf(vi[k].z * inv_i); oi[4*k+3] = f2bf(vi[k].w * inv_i);
        oj[4*k+0] = f2bf(vj[k].x * inv_j); oj[4*k+1] = f2bf(vj[k].y * inv_j);
        oj[4*k+2] = f2bf(vj[k].z * inv_j); oj[4*k+3] = f2bf(vj[k].w * inv_j);
    }
    ushort* ri = reps + (size_t)b * D_DIM + lane * 16;
    ushort* rj = reps + (size_t)(b + B_ROWS) * D_DIM + lane * 16;
    *(bf16x8*)(ri)     = *(bf16x8*)(oi);
    *(bf16x8*)(ri + 8) = *(bf16x8*)(oi + 8);
    *(bf16x8*)(rj)     = *(bf16x8*)(oj);
    *(bf16x8*)(rj + 8) = *(bf16x8*)(oj + 8);
}

// ---------------------------------------------------------------------------
// Kernel 2: fused sim = Z.Z^T -> exp(s/T) -> diag-mask -> column-sum into
// denom[] (sim symmetric: col sums == row sums).
// 128x128 tile, BK=32, 16x16x32 bf16 MFMA, global_load_lds width-16 staging.
// LDS layout: row stride 32 bf16 (64 B, NO pad — required by global_load_lds);
// chunk c (16 B) of row r stored at slot c ^ ((r>>1)&3) — XOR swizzle done on
// the GLOBAL source address, spreads ds_read_b128 over 8 bank-groups (2-way
// aliasing = free) instead of 2 (8-way).
// ---------------------------------------------------------------------------
#define BM 128
#define BN 128
#define BK 32
#define COL_SPLIT 16
#define COLS_PER_BLOCK (N_ROWS / COL_SPLIT)   // 512

__global__ __launch_bounds__(256)
void sim_denom_kernel(const ushort* __restrict__ reps,
                      float* __restrict__ denom) {
    const int rt = blockIdx.x & 63;       // row tile index
    const int cs = blockIdx.x >> 6;       // col split index
    const int rowBase  = rt * BM;
    const int colStart = cs * COLS_PER_BLOCK;

    const int t    = threadIdx.x;
    const int lane = t & 63;
    const int wave = t >> 6;
    const int wr   = wave >> 1;           // wave row quadrant (0/1)
    const int wc   = wave & 1;            // wave col quadrant (0/1)
    const int quad = lane >> 4;           // 0..3
    const int l15  = lane & 15;

    __shared__ ushort Asmem[BM * BK];     // 8 KB, stride 32
    __shared__ ushort Bsmem[BN * BK];     // 8 KB

    // staging lane map (constant across kb): lane i loads row seg*16+(i>>2),
    // global chunk (i&3) ^ ((i>>3)&3), landing at LDS slot (i&3) of that row.
    const int rl = lane >> 2;                       // row within segment
    const int cg = (lane & 3) ^ ((lane >> 3) & 3);  // swizzled global chunk
    const int seg0 = wave * 2, seg1 = wave * 2 + 1;
    const size_t gA0 = (size_t)(rowBase + seg0 * 16 + rl) * D_DIM + cg * 8;
    const size_t gA1 = (size_t)(rowBase + seg1 * 16 + rl) * D_DIM + cg * 8;

    for (int ci = 0; ci < COLS_PER_BLOCK / BN; ci++) {
        const int colBase = colStart + ci * BN;
        const size_t gB0 = (size_t)(colBase + seg0 * 16 + rl) * D_DIM + cg * 8;
        const size_t gB1 = (size_t)(colBase + seg1 * 16 + rl) * D_DIM + cg * 8;

        f32x4 acc[4][4];
        #pragma unroll
        for (int mi = 0; mi < 4; mi++)
            #pragma unroll
            for (int ni = 0; ni < 4; ni++)
                acc[mi][ni] = (f32x4){0.f, 0.f, 0.f, 0.f};

        for (int kb = 0; kb < D_DIM; kb += BK) {
            __syncthreads();   // prev iter's ds_reads done before overwrite
            load_lds16(reps + gA0 + kb, Asmem + seg0 * 512);
            load_lds16(reps + gA1 + kb, Asmem + seg1 * 512);
            load_lds16(reps + gB0 + kb, Bsmem + seg0 * 512);
            load_lds16(reps + gB1 + kb, Bsmem + seg1 * 512);
            __syncthreads();   // drains vmcnt (compiler inserts waitcnt)

            bf16x8 af[4], bfr[4];
            #pragma unroll
            for (int mi = 0; mi < 4; mi++) {
                const int r = wr * 64 + mi * 16 + l15;
                af[mi] = *(const bf16x8*)(Asmem + r * 32 + (quad ^ ((r >> 1) & 3)) * 8);
            }
            #pragma unroll
            for (int ni = 0; ni < 4; ni++) {
                const int r = wc * 64 + ni * 16 + l15;
                bfr[ni] = *(const bf16x8*)(Bsmem + r * 32 + (quad ^ ((r >> 1) & 3)) * 8);
            }

            #pragma unroll
            for (int mi = 0; mi < 4; mi++)
                #pragma unroll
                for (int ni = 0; ni < 4; ni++)
                    acc[mi][ni] = __builtin_amdgcn_mfma_f32_16x16x32_bf16(
                        af[mi], bfr[ni], acc[mi][ni], 0, 0, 0);
        }

        // Epilogue: e = exp(s/T), mask diagonal, per-lane partial column sums
        // (C layout: col = lane&15, row = quad*4 + reg).
        float cs_part[4] = {0.f, 0.f, 0.f, 0.f};
        #pragma unroll
        for (int mi = 0; mi < 4; mi++) {
            const int rowA = rowBase + wr * 64 + mi * 16 + quad * 4;
            #pragma unroll
            for (int ni = 0; ni < 4; ni++) {
                const int col = colBase + wc * 64 + ni * 16 + l15;
                const f32x4 a = acc[mi][ni];
                #pragma unroll
                for (int r = 0; r < 4; r++) {
                    float e = __expf(a[r] * TEMP_INV);
                    if (rowA + r == col) e = 0.0f;   // neg_mask diagonal
                    cs_part[ni] += e;
                }
            }
        }
        #pragma unroll
        for (int ni = 0; ni < 4; ni++) {   // reduce across the 4 quads
            float v = cs_part[ni];
            v += __shfl_xor(v, 16);
            v += __shfl_xor(v, 32);
            cs_part[ni] = v;
        }
        if (quad == 0) {
            #pragma unroll
            for (int ni = 0; ni < 4; ni++) {
                const int col = colBase + wc * 64 + ni * 16 + l15;
                atomicAdd(denom + col, cs_part[ni]);
            }
        }
    }
}

// ---------------------------------------------------------------------------
// Kernel 3: loss = mean over 2B rows of (log(denom) - pos/T). Single block.
// ---------------------------------------------------------------------------
__global__ __launch_bounds__(256)
void loss_kernel(const float* __restrict__ denom,
                 const float* __restrict__ pos,
                 float* __restrict__ out) {
    const int t = threadIdx.x;
    float s = 0.f;
    for (int i = t; i < N_ROWS; i += 256) {
        const float p = pos[i & (B_ROWS - 1)];
        s += logf(denom[i]) - p * TEMP_INV;
    }
    #pragma unroll
    for (int off = 32; off >= 1; off >>= 1) s += __shfl_xor(s, off);
    __shared__ float red[4];
    if ((t & 63) == 0) red[t >> 6] = s;
    __syncthreads();
    if (t == 0) out[0] = (red[0] + red[1] + red[2] + red[3]) / (float)N_ROWS;
}

// ---------------------------------------------------------------------------
extern "C" void kernel_launch(void* const* d_in, const int* in_sizes, int n_in,
                              void* d_out, int out_size, void* d_ws, size_t ws_size,
                              hipStream_t stream) {
    const float* emb_i = (const float*)d_in[0];
    const float* emb_j = (const float*)d_in[1];

    ushort* reps  = (ushort*)d_ws;                                    // 16 MB bf16 [8192][1024]
    float*  pos   = (float*)((char*)d_ws + (size_t)N_ROWS * D_DIM * sizeof(ushort)); // 16 KB
    float*  denom = pos + B_ROWS;                                     // 32 KB
    float*  out   = (float*)d_out;

    normalize_kernel<<<B_ROWS / 4, 256, 0, stream>>>(emb_i, emb_j, reps, pos, denom);
    sim_denom_kernel<<<64 * COL_SPLIT, 256, 0, stream>>>(reps, denom);
    loss_kernel<<<1, 256, 0, stream>>>(denom, pos, out);
}